// Round 1
// baseline (435.079 us; speedup 1.0000x reference)
//
#include <hip/hip_runtime.h>
#include <hip/hip_bf16.h>
#include <stdint.h>

typedef __bf16 bf16_t;
typedef __bf16 bf16x8 __attribute__((ext_vector_type(8)));
typedef __bf16 bf16x4v __attribute__((ext_vector_type(4)));
typedef float f32x4 __attribute__((ext_vector_type(4)));

#define DEV __device__ __forceinline__

static constexpr int B_ = 2, S_ = 4096, E_ = 768, H_ = 12, D_ = 64;
static constexpr int WINDOW_ = 128;

// ---------- async 16B global -> LDS ----------
DEV void gload_lds16(const void* g, void* l) {
    __builtin_amdgcn_global_load_lds(
        (const __attribute__((address_space(1))) uint32_t*)g,
        (__attribute__((address_space(3))) uint32_t*)l, 16, 0, 0);
}

// ---------- fp32 -> bf16 convert ----------
__global__ void k_cvt(const float* __restrict__ in, bf16_t* __restrict__ out, int n) {
    int i = (blockIdx.x * blockDim.x + threadIdx.x) * 4;
    if (i < n) {
        float4 v = *(const float4*)(in + i);
        bf16x4v o;
        o[0] = (bf16_t)v.x; o[1] = (bf16_t)v.y; o[2] = (bf16_t)v.z; o[3] = (bf16_t)v.w;
        *(bf16x4v*)(out + i) = o;
    }
}

// ---------- NT GEMM: C[m][n] = sum_k A[m][k] * Bw[n][k] + bias[n] ----------
// EPI 0: scatter into q/k/v [B,H,S,D] bf16 (q scaled by 0.125)
// EPI 1: fp32 output [M][N]
template<int EPI>
__global__ void k_gemm(const bf16_t* __restrict__ A, const bf16_t* __restrict__ Bw,
                       const float* __restrict__ bias,
                       bf16_t* __restrict__ qb, bf16_t* __restrict__ kb, bf16_t* __restrict__ vb,
                       float* __restrict__ outf,
                       int M, int N, int K, int mtiles) {
    __shared__ bf16_t As[128 * 64];
    __shared__ bf16_t Bs[128 * 64];
    int bid = blockIdx.x;
    int tm = bid % mtiles, tn = bid / mtiles;
    int m0 = tm * 128, n0 = tn * 128;
    int t = threadIdx.x;
    int lane = t & 63, wid = t >> 6;
    int l15 = lane & 15, l4 = lane >> 4;
    int wm = (wid & 1) * 64, wn = (wid >> 1) * 64;

    f32x4 acc[4][4];
#pragma unroll
    for (int i = 0; i < 4; ++i)
#pragma unroll
        for (int j = 0; j < 4; ++j) acc[i][j] = f32x4{0.f, 0.f, 0.f, 0.f};

    for (int kt = 0; kt < K; kt += 64) {
        __syncthreads();
        // stage A,B tiles 128x64 bf16 each; LDS linear dest, swizzled global source:
        // LDS[row][chunk p] holds k-chunk (p ^ (row&7)), chunk = 8 bf16 = 16B
#pragma unroll
        for (int c = 0; c < 4; ++c) {
            int idx = t + 256 * c;         // 0..1023
            int row = idx >> 3, part = idx & 7;
            int kc = 8 * (part ^ (row & 7));
            gload_lds16(A + (long)(m0 + row) * K + kt + kc, (char*)As + idx * 16);
            gload_lds16(Bw + (long)(n0 + row) * K + kt + kc, (char*)Bs + idx * 16);
        }
        __syncthreads();
#pragma unroll
        for (int kk = 0; kk < 2; ++kk) {
            bf16x8 af[4], bfr[4];
#pragma unroll
            for (int i = 0; i < 4; ++i) {
                int row = wm + i * 16 + l15;
                int off = row * 128 + ((16 * (kk * 4 + l4)) ^ ((row & 7) << 4));
                af[i] = *(const bf16x8*)((const char*)As + off);
                int rowb = wn + i * 16 + l15;
                int offb = rowb * 128 + ((16 * (kk * 4 + l4)) ^ ((rowb & 7) << 4));
                bfr[i] = *(const bf16x8*)((const char*)Bs + offb);
            }
#pragma unroll
            for (int i = 0; i < 4; ++i)
#pragma unroll
                for (int j = 0; j < 4; ++j)
                    acc[i][j] = __builtin_amdgcn_mfma_f32_16x16x32_bf16(af[i], bfr[j], acc[i][j], 0, 0, 0);
        }
    }

    // epilogue: D row = (lane>>4)*4 + r, col = lane&15
#pragma unroll
    for (int i = 0; i < 4; ++i) {
#pragma unroll
        for (int j = 0; j < 4; ++j) {
            int n = n0 + wn + j * 16 + l15;
            float bv = bias[n];
#pragma unroll
            for (int r = 0; r < 4; ++r) {
                int m = m0 + wm + i * 16 + l4 * 4 + r;
                float v = acc[i][j][r] + bv;
                if (EPI == 0) {
                    int sel = n / 768, nn = n % 768;
                    int h = nn >> 6, d = nn & 63;
                    int b = m >> 12, s = m & 4095;
                    long o = ((long)(b * H_ + h) * S_ + s) * D_ + d;
                    if (sel == 0) qb[o] = (bf16_t)(v * 0.125f);
                    else if (sel == 1) kb[o] = (bf16_t)v;
                    else vb[o] = (bf16_t)v;
                } else {
                    outf[(long)m * 768 + n] = v;
                }
            }
        }
    }
}

// ---------- transpose v [BH][S][D] -> vt [BH][D][S] ----------
__global__ void k_transpose(const bf16_t* __restrict__ v, bf16_t* __restrict__ vt) {
    __shared__ bf16_t tile[64][72];
    int bid = blockIdx.x;
    int bh = bid >> 6, st = bid & 63;
    int s0 = st * 64;
    int t = threadIdx.x;
    const bf16_t* src = v + ((long)bh * S_ + s0) * 64;
    int row = t >> 2, c0 = (t & 3) * 16;
    bf16x8 a0 = *(const bf16x8*)(src + row * 64 + c0);
    bf16x8 a1 = *(const bf16x8*)(src + row * 64 + c0 + 8);
    *(bf16x8*)&tile[row][c0] = a0;
    *(bf16x8*)&tile[row][c0 + 8] = a1;
    __syncthreads();
    int d = t >> 2;
    bf16_t* dst = vt + ((long)bh * 64 + d) * S_ + s0 + c0;
    bf16x8 o0, o1;
#pragma unroll
    for (int j = 0; j < 8; ++j) o0[j] = tile[c0 + j][d];
#pragma unroll
    for (int j = 0; j < 8; ++j) o1[j] = tile[c0 + 8 + j][d];
    *(bf16x8*)dst = o0;
    *(bf16x8*)(dst + 8) = o1;
}

// ---------- attention: out[b,s,h*64+d], mask: |i-j| <= 128 BANNED ----------
__global__ void k_attn(const bf16_t* __restrict__ q, const bf16_t* __restrict__ k,
                       const bf16_t* __restrict__ vt, bf16_t* __restrict__ ao) {
    __shared__ bf16_t Ks[64 * 64];   // [key][d], swizzled
    __shared__ bf16_t Vs[64 * 64];   // [d][key], swizzled
    __shared__ bf16_t Ps[4][16 * 64];// per-wave [q][key], swizzled
    int bid = blockIdx.x;
    int bh = bid >> 6;
    int qt = bid & 63;
    int q0 = qt * 64;
    int b = bh / H_, h = bh % H_;
    int t = threadIdx.x, lane = t & 63, wid = t >> 6;
    int l15 = lane & 15, l4 = lane >> 4;

    const bf16_t* qh = q + (long)bh * S_ * D_;
    const bf16_t* kh = k + (long)bh * S_ * D_;
    const bf16_t* vh = vt + (long)bh * D_ * S_;

    // Q fragments (16 rows per wave), q already scaled by 1/8
    int qrow = q0 + wid * 16 + l15;
    bf16x8 qf[2];
    qf[0] = *(const bf16x8*)(qh + (long)qrow * 64 + 8 * l4);
    qf[1] = *(const bf16x8*)(qh + (long)qrow * 64 + 32 + 8 * l4);

    f32x4 o[4];
#pragma unroll
    for (int ns = 0; ns < 4; ++ns) o[ns] = f32x4{0.f, 0.f, 0.f, 0.f};
    float m[4] = {-1e30f, -1e30f, -1e30f, -1e30f};
    float sum[4] = {0.f, 0.f, 0.f, 0.f};

    bf16_t* pw = &Ps[wid][0];
    int iq = q0 + wid * 16 + l4 * 4;

    for (int kt = 0; kt < 64; ++kt) {
        int k0 = kt * 64;
        int dq = k0 - q0; if (dq < 0) dq = -dq;
        if (dq <= 65) continue;   // tile fully inside banned band (block-uniform)

        __syncthreads();
#pragma unroll
        for (int c = 0; c < 2; ++c) {
            int idx = t + 256 * c;       // 0..511
            int row = idx >> 3, part = idx & 7;
            int kc = 8 * (part ^ (row & 7));
            gload_lds16(kh + (long)(k0 + row) * 64 + kc, (char*)Ks + idx * 16);
            gload_lds16(vh + (long)row * S_ + k0 + kc, (char*)Vs + idx * 16);
        }
        __syncthreads();

        // QK^T: s[ks] holds S[q = l4*4+r][key = k0 + ks*16 + l15]
        f32x4 s[4];
#pragma unroll
        for (int ks = 0; ks < 4; ++ks) {
            s[ks] = f32x4{0.f, 0.f, 0.f, 0.f};
#pragma unroll
            for (int kk = 0; kk < 2; ++kk) {
                int row = ks * 16 + l15;
                int off = row * 128 + ((16 * (kk * 4 + l4)) ^ ((row & 7) << 4));
                bf16x8 kf = *(const bf16x8*)((const char*)Ks + off);
                s[ks] = __builtin_amdgcn_mfma_f32_16x16x32_bf16(qf[kk], kf, s[ks], 0, 0, 0);
            }
        }

        // mask + online softmax (rows lane-replicated within 16-lane groups)
        float p[4][4];
        float tm_[4] = {-1e30f, -1e30f, -1e30f, -1e30f};
#pragma unroll
        for (int ks = 0; ks < 4; ++ks) {
            int j = k0 + ks * 16 + l15;
#pragma unroll
            for (int r = 0; r < 4; ++r) {
                int dd = iq + r - j; int ad = dd < 0 ? -dd : dd;
                float sv = (ad <= WINDOW_) ? -1e30f : s[ks][r];
                p[ks][r] = sv;
                tm_[r] = fmaxf(tm_[r], sv);
            }
        }
#pragma unroll
        for (int r = 0; r < 4; ++r) {
            tm_[r] = fmaxf(tm_[r], __shfl_xor(tm_[r], 1));
            tm_[r] = fmaxf(tm_[r], __shfl_xor(tm_[r], 2));
            tm_[r] = fmaxf(tm_[r], __shfl_xor(tm_[r], 4));
            tm_[r] = fmaxf(tm_[r], __shfl_xor(tm_[r], 8));
        }
#pragma unroll
        for (int r = 0; r < 4; ++r) {
            float mn = fmaxf(m[r], tm_[r]);
            float f = __expf(m[r] - mn);
            m[r] = mn;
            sum[r] *= f;
#pragma unroll
            for (int ks = 0; ks < 4; ++ks) {
                float pv = __expf(p[ks][r] - mn);
                pv = (p[ks][r] <= -1e29f) ? 0.f : pv;
                p[ks][r] = pv;
            }
            float lsum = p[0][r] + p[1][r] + p[2][r] + p[3][r];
            lsum += __shfl_xor(lsum, 1);
            lsum += __shfl_xor(lsum, 2);
            lsum += __shfl_xor(lsum, 4);
            lsum += __shfl_xor(lsum, 8);
            sum[r] += lsum;
#pragma unroll
            for (int ns = 0; ns < 4; ++ns) o[ns][r] *= f;
        }

        // P -> LDS (wave-private, swizzled)
#pragma unroll
        for (int ks = 0; ks < 4; ++ks) {
#pragma unroll
            for (int r = 0; r < 4; ++r) {
                int qr = l4 * 4 + r;
                int byteoff = qr * 128 + ((((ks * 16 + l15) * 2)) ^ ((qr & 7) << 4));
                *(bf16_t*)((char*)pw + byteoff) = (bf16_t)p[ks][r];
            }
        }
        asm volatile("s_waitcnt lgkmcnt(0)" ::: "memory");
        __builtin_amdgcn_sched_barrier(0);

        // PV: o[ns] += P[16q x 64key] * V[64key x 16d]
#pragma unroll
        for (int ns = 0; ns < 4; ++ns) {
#pragma unroll
            for (int kk = 0; kk < 2; ++kk) {
                int offp = l15 * 128 + ((16 * (kk * 4 + l4)) ^ ((l15 & 7) << 4));
                bf16x8 pf = *(const bf16x8*)((const char*)pw + offp);
                int drow = ns * 16 + l15;
                int offv = drow * 128 + ((16 * (kk * 4 + l4)) ^ ((drow & 7) << 4));
                bf16x8 vf = *(const bf16x8*)((const char*)Vs + offv);
                o[ns] = __builtin_amdgcn_mfma_f32_16x16x32_bf16(pf, vf, o[ns], 0, 0, 0);
            }
        }
    }

    // finalize + write [B,S,E] bf16
    float inv[4];
#pragma unroll
    for (int r = 0; r < 4; ++r) inv[r] = 1.0f / sum[r];
#pragma unroll
    for (int ns = 0; ns < 4; ++ns) {
#pragma unroll
        for (int r = 0; r < 4; ++r) {
            int srow = q0 + wid * 16 + l4 * 4 + r;
            int e = h * 64 + ns * 16 + l15;
            ao[((long)b * S_ + srow) * E_ + e] = (bf16_t)(o[ns][r] * inv[r]);
        }
    }
}

extern "C" void kernel_launch(void* const* d_in, const int* in_sizes, int n_in,
                              void* d_out, int out_size, void* d_ws, size_t ws_size,
                              hipStream_t stream) {
    const float* x     = (const float*)d_in[0];
    const float* w_in  = (const float*)d_in[1];
    const float* b_in  = (const float*)d_in[2];
    const float* w_out = (const float*)d_in[3];
    const float* b_out = (const float*)d_in[4];
    float* out = (float*)d_out;

    char* ws = (char*)d_ws;
    // ws layout (bytes):
    bf16_t* xb  = (bf16_t*)(ws + 0);          // 12582912  (reused as attn-out after GEMM1)
    bf16_t* wib = (bf16_t*)(ws + 12582912);   // 3538944
    bf16_t* wob = (bf16_t*)(ws + 16121856);   // 1179648
    bf16_t* qb  = (bf16_t*)(ws + 17301504);   // 12582912
    bf16_t* kb  = (bf16_t*)(ws + 29884416);   // 12582912
    bf16_t* vb  = (bf16_t*)(ws + 42467328);   // 12582912
    bf16_t* vtb = (bf16_t*)(ws + 55050240);   // 12582912  -> total 67633152
    bf16_t* ao  = xb;                          // alias: xb dead after GEMM1

    k_cvt<<<6144, 256, 0, stream>>>(x, xb, 6291456);
    k_cvt<<<1728, 256, 0, stream>>>(w_in, wib, 1769472);
    k_cvt<<<576, 256, 0, stream>>>(w_out, wob, 589824);

    // QKV projection: M=8192, N=2304, K=768
    k_gemm<0><<<64 * 18, 256, 0, stream>>>(xb, wib, b_in, qb, kb, vb, nullptr,
                                           8192, 2304, 768, 64);
    k_transpose<<<24 * 64, 256, 0, stream>>>(vb, vtb);
    k_attn<<<24 * 64, 256, 0, stream>>>(qb, kb, vtb, ao);
    // out projection: M=8192, N=768, K=768
    k_gemm<1><<<64 * 6, 256, 0, stream>>>(ao, wob, b_out, nullptr, nullptr, nullptr, out,
                                          8192, 768, 768, 64);
}